// Round 5
// baseline (7126.312 us; speedup 1.0000x reference)
//
#include <hip/hip_runtime.h>
#include <hip/hip_fp16.h>

// Problem constants
#define TT 2048
#define II 1739
#define HN 256
#define H3 768

typedef _Float16 h8v __attribute__((ext_vector_type(8)));
typedef float f4v __attribute__((ext_vector_type(4)));

// C[M,N] = A[M,K] @ B[N,K]^T + bias1[n] + (n < b2lim ? bias2[n] : 0)
// 64x64 tile, 256 threads, 4x4 micro-tile per thread.
__global__ __launch_bounds__(256) void gemm_abt(
    const float* __restrict__ A, int M, int K,
    const float* __restrict__ B, int N,
    const float* __restrict__ bias1, const float* __restrict__ bias2, int b2lim,
    float* __restrict__ C) {
  __shared__ float As[16][64];
  __shared__ float Bs[16][64];
  const int tid = threadIdx.x;
  const int m0 = blockIdx.y * 64, n0 = blockIdx.x * 64;
  const int lr = tid >> 2;        // 0..63  (row within tile for loads)
  const int lk = (tid & 3) * 4;   // 0,4,8,12
  const int cx = tid & 15, cy = tid >> 4;
  float acc[4][4] = {};

  for (int k0 = 0; k0 < K; k0 += 16) {
#pragma unroll
    for (int i = 0; i < 4; ++i) {
      int k = k0 + lk + i;
      As[lk + i][lr] = (k < K) ? A[(size_t)(m0 + lr) * K + k] : 0.f;
      int bn = n0 + lr;
      Bs[lk + i][lr] = (k < K && bn < N) ? B[(size_t)bn * K + k] : 0.f;
    }
    __syncthreads();
#pragma unroll
    for (int k = 0; k < 16; ++k) {
      float4 av = *(const float4*)&As[k][cy * 4];
      float4 bv = *(const float4*)&Bs[k][cx * 4];
      const float aa[4] = {av.x, av.y, av.z, av.w};
      const float bb[4] = {bv.x, bv.y, bv.z, bv.w};
#pragma unroll
      for (int i = 0; i < 4; ++i)
#pragma unroll
        for (int j = 0; j < 4; ++j) acc[i][j] = fmaf(aa[i], bb[j], acc[i][j]);
    }
    __syncthreads();
  }
#pragma unroll
  for (int i = 0; i < 4; ++i) {
    int m = m0 + cy * 4 + i;
#pragma unroll
    for (int j = 0; j < 4; ++j) {
      int n = n0 + cx * 4 + j;
      if (n < N) {
        float b = bias1 ? bias1[n] : 0.f;
        if (bias2 && n < b2lim) b += bias2[n];
        C[(size_t)m * N + n] = acc[i][j] + b;
      }
    }
  }
}

// Sequential GRU scan on a single CU: 256 threads = 4 waves = 1 wave/SIMD,
// 512 regs/wave (unified VGPR+AGPR). The whole W_hh (f16, 393 KB) lives in
// the CU register file with NO spill: 384 regs/thread of A-fragments.
// Wave wv owns units u = 64wv..64wv+63 and computes all three gate rows:
// r-rows u (tiles 0-3), z-rows 256+u (tiles 4-7), n-rows 512+u (tiles 8-11)
// via v_mfma_f32_16x16x32_f16. Broadcast-B: every lane loads the same h
// k-slice (per quad-row q), so every D column equals W.h.
// Exactly one lane per hidden unit (u = tid) -> unpredicated gates.
// Matvec->gate handoff is wave-local (in-order DS pipe, lgkmcnt wait only);
// ONE lgkm-only barrier per step; hbuf double-buffered for cross-wave WAR.
__global__ __launch_bounds__(256) __attribute__((amdgpu_waves_per_eu(1, 1)))
void gru_seq(
    const float* __restrict__ xp,      // [T, 768]
    const float* __restrict__ Whh,     // [768, 256]
    const float* __restrict__ bhh,     // [768]
    const float* __restrict__ h0,      // [256] or nullptr (zeros)
    float* __restrict__ hs_out,        // [T, 256] or nullptr
    float* __restrict__ hT_out) {      // [256] or nullptr
  __shared__ _Float16 hbuf[2][HN];  // double-buffered h (f16)
  __shared__ float hw[4][192];      // per-wave matvec out: [wv][64r|64z|64n]

  const int tid = threadIdx.x;
  const int lane = tid & 63;
  const int wv = tid >> 6;
  const int q = lane >> 4;    // quad-row 0..3
  const int ml = lane & 15;   // col within 16 (redundant dim)
  const int u = tid;          // owned hidden unit (1:1)

  // A-fragments: tile i = gi*4+ii (gi: 0=r,1=z,2=n; ii: 16-row subtile).
  // afrag[i][kc] = W[256*gi + 64*wv + 16*ii + ml][32*kc + 8*q + j], j=0..7
  h8v afrag[12][8];
#pragma unroll
  for (int i = 0; i < 12; ++i) {
    const int gi = i >> 2, ii = i & 3;
    const float* wr = Whh + (size_t)(256 * gi + 64 * wv + 16 * ii + ml) * HN + 8 * q;
#pragma unroll
    for (int kc = 0; kc < 8; ++kc) {
      const float* wp = wr + 32 * kc;
      float4 a = *(const float4*)wp;
      float4 b = *(const float4*)(wp + 4);
      afrag[i][kc] = h8v{(_Float16)a.x, (_Float16)a.y, (_Float16)a.z, (_Float16)a.w,
                         (_Float16)b.x, (_Float16)b.y, (_Float16)b.z, (_Float16)b.w};
    }
  }

  float hj = h0 ? h0[u] : 0.f;
  const float bhn = bhh[2 * HN + u];
  hbuf[0][u] = (_Float16)hj;
  __syncthreads();

  // Prefetch xp for step 0.
  float xr = xp[u], xz = xp[HN + u], xn = xp[2 * HN + u];

  for (int t = 0; t < TT; ++t) {
    // Prefetch next step's x-projection (never drained by the lgkm barrier).
    float nxr = 0.f, nxz = 0.f, nxn = 0.f;
    if (t + 1 < TT) {
      const float* xpt = xp + (size_t)(t + 1) * H3 + u;
      nxr = xpt[0];
      nxz = xpt[HN];
      nxn = xpt[2 * HN];
    }

    const _Float16* hb = hbuf[t & 1];

    // Two groups of 6 tiles to cap live acc regs; hv reloaded per group
    // (broadcast reads, cheap). Within a group: 6 indep MFMA chains.
#pragma unroll
    for (int grp = 0; grp < 2; ++grp) {
      f4v acc[6];
#pragma unroll
      for (int i = 0; i < 6; ++i) acc[i] = f4v{0.f, 0.f, 0.f, 0.f};
#pragma unroll
      for (int ph = 0; ph < 2; ++ph) {
        h8v hv[4];
#pragma unroll
        for (int c = 0; c < 4; ++c)
          hv[c] = *(const h8v*)((const char*)hb + 64 * (ph * 4 + c) + 16 * q);
#pragma unroll
        for (int c = 0; c < 4; ++c) {
#pragma unroll
          for (int i = 0; i < 6; ++i)
            acc[i] = __builtin_amdgcn_mfma_f32_16x16x32_f16(
                afrag[grp * 6 + i][ph * 4 + c], hv[c], acc[i], 0, 0, 0);
        }
      }
      // D row = 4q+reg of tile -> hw[wv][64*gi + 16*ii + 4q + reg].
      if (ml == 0) {
#pragma unroll
        for (int i = 0; i < 6; ++i) {
          const int ti = grp * 6 + i;
          const int gi = ti >> 2, ii = ti & 3;
          *(f4v*)&hw[wv][64 * gi + 16 * ii + 4 * q] = acc[i];
        }
      }
    }
    // Wave-local: DS pipe is in-order; wait own writes, no barrier.
    asm volatile("s_waitcnt lgkmcnt(0)" ::: "memory");

    // Gates: every lane owns unit u = tid; inputs wave-local.
    {
      float hr = hw[wv][lane];
      float hz = hw[wv][64 + lane];
      float hn = hw[wv][128 + lane];
      float r = 1.f / (1.f + __expf(-(xr + hr)));
      float z = 1.f / (1.f + __expf(-(xz + hz)));
      float nv = 2.f / (1.f + __expf(-2.f * (xn + r * (hn + bhn)))) - 1.f;
      hj = (1.f - z) * nv + z * hj;
      if (hs_out) hs_out[(size_t)t * HN + u] = hj;
      hbuf[(t + 1) & 1][u] = (_Float16)hj;
    }
    xr = nxr; xz = nxz; xn = nxn;
    // lgkm-only barrier: orders hbuf writes vs next step's reads without
    // draining vmcnt (xp prefetch + hs stores stay in flight).
    asm volatile("s_waitcnt lgkmcnt(0)\n\ts_barrier" ::: "memory");
  }
  if (hT_out) hT_out[u] = hj;
}

extern "C" void kernel_launch(void* const* d_in, const int* in_sizes, int n_in,
                              void* d_out, int out_size, void* d_ws, size_t ws_size,
                              hipStream_t stream) {
  const float* x     = (const float*)d_in[0];   // [1, 2048, 1739]
  const float* Wih_e = (const float*)d_in[2];   // [768, 1739]
  const float* Whh_e = (const float*)d_in[3];   // [768, 256]
  const float* bih_e = (const float*)d_in[4];   // [768]
  const float* bhh_e = (const float*)d_in[5];   // [768]
  const float* Wih_d = (const float*)d_in[6];
  const float* Whh_d = (const float*)d_in[7];
  const float* bih_d = (const float*)d_in[8];
  const float* bhh_d = (const float*)d_in[9];
  const float* Wout  = (const float*)d_in[10];  // [1739, 256]
  const float* bout  = (const float*)d_in[11];  // [1739]
  float* out = (float*)d_out;                   // [2048, 1, 1739]

  float* ws = (float*)d_ws;
  float* xpe  = ws;                              // 2048*768
  float* xpd  = xpe + (size_t)TT * H3;           // 2048*768
  float* hs   = xpd + (size_t)TT * H3;           // 2048*256
  float* henc = hs + (size_t)TT * HN;            // 256

  dim3 blk(256);
  // x-projections (b_hh folded in for r,z rows; n rows get b_ih only)
  gemm_abt<<<dim3(12, 32), blk, 0, stream>>>(x, TT, II, Wih_e, H3, bih_e, bhh_e, 2 * HN, xpe);
  gemm_abt<<<dim3(12, 32), blk, 0, stream>>>(x, TT, II, Wih_d, H3, bih_d, bhh_d, 2 * HN, xpd);
  // encoder scan -> henc
  gru_seq<<<1, 256, 0, stream>>>(xpe, Whh_e, bhh_e, nullptr, nullptr, henc);
  // decoder scan -> hs
  gru_seq<<<1, 256, 0, stream>>>(xpd, Whh_d, bhh_d, henc, hs, nullptr);
  // output projection
  gemm_abt<<<dim3(28, 32), blk, 0, stream>>>(hs, TT, HN, Wout, II, bout, nullptr, 0, out);
}

// Round 6
// 6271.770 us; speedup vs baseline: 1.1363x; 1.1363x over previous
//
#include <hip/hip_runtime.h>
#include <hip/hip_fp16.h>

// Problem constants
#define TT 2048
#define II 1739
#define HN 256
#define H3 768

typedef _Float16 h2 __attribute__((ext_vector_type(2)));

__device__ __forceinline__ float fdot2(h2 a, h2 b, float c) {
  return __builtin_amdgcn_fdot2(a, b, c, false);
}

template <int CTRL>
__device__ __forceinline__ float dpp_qperm(float v) {
  int r = __builtin_amdgcn_update_dpp(0, __builtin_bit_cast(int, v), CTRL, 0xF, 0xF, true);
  return __builtin_bit_cast(float, r);
}

// C[M,N] = A[M,K] @ B[N,K]^T + bias1[n] + (n < b2lim ? bias2[n] : 0)
// 64x64 tile, 256 threads, 4x4 micro-tile per thread.
__global__ __launch_bounds__(256) void gemm_abt(
    const float* __restrict__ A, int M, int K,
    const float* __restrict__ B, int N,
    const float* __restrict__ bias1, const float* __restrict__ bias2, int b2lim,
    float* __restrict__ C) {
  __shared__ float As[16][64];
  __shared__ float Bs[16][64];
  const int tid = threadIdx.x;
  const int m0 = blockIdx.y * 64, n0 = blockIdx.x * 64;
  const int lr = tid >> 2;        // 0..63  (row within tile for loads)
  const int lk = (tid & 3) * 4;   // 0,4,8,12
  const int cx = tid & 15, cy = tid >> 4;
  float acc[4][4] = {};

  for (int k0 = 0; k0 < K; k0 += 16) {
#pragma unroll
    for (int i = 0; i < 4; ++i) {
      int k = k0 + lk + i;
      As[lk + i][lr] = (k < K) ? A[(size_t)(m0 + lr) * K + k] : 0.f;
      int bn = n0 + lr;
      Bs[lk + i][lr] = (k < K && bn < N) ? B[(size_t)bn * K + k] : 0.f;
    }
    __syncthreads();
#pragma unroll
    for (int k = 0; k < 16; ++k) {
      float4 av = *(const float4*)&As[k][cy * 4];
      float4 bv = *(const float4*)&Bs[k][cx * 4];
      const float aa[4] = {av.x, av.y, av.z, av.w};
      const float bb[4] = {bv.x, bv.y, bv.z, bv.w};
#pragma unroll
      for (int i = 0; i < 4; ++i)
#pragma unroll
        for (int j = 0; j < 4; ++j) acc[i][j] = fmaf(aa[i], bb[j], acc[i][j]);
    }
    __syncthreads();
  }
#pragma unroll
  for (int i = 0; i < 4; ++i) {
    int m = m0 + cy * 4 + i;
#pragma unroll
    for (int j = 0; j < 4; ++j) {
      int n = n0 + cx * 4 + j;
      if (n < N) {
        float b = bias1 ? bias1[n] : 0.f;
        if (bias2 && n < b2lim) b += bias2[n];
        C[(size_t)m * N + n] = acc[i][j] + b;
      }
    }
  }
}

// Sequential GRU scan on one CU: 512 threads = 8 waves = 2 waves/SIMD,
// 256-reg/wave budget (amdgpu_waves_per_eu(2,2)). Engine: v_dot2_f32_f16
// (2 MACs/lane/instr) with W_hh as f16 pairs in ARCH VGPRs (192/thread).
// MFMA rejected: matvec uses 1/16 of B columns -> 1860 cyc/step floor vs
// dot2's 768 (measured across R2-R4).
// Thread = (unit-pair p = tid>>2 in [0,128), kc = tid&3). Owns 6 rows
// {2p,2p+1,256+2p,256+2p+1,512+2p,512+2p+1} x k-chunk [64kc,64kc+64).
// Quad DPP reduce (kc xor1,xor2) -> kc==0 lane has complete r,z,n for both
// units -> gates computed in-register (wave-local, no LDS round-trip).
// ONE lgkm-only barrier per step (xp prefetch + hs stores never drained);
// h double-buffered in LDS as f16, kc-chunks padded to 144 B stride
// (banks {0,4,8,12}) -> ds_read_b128 conflict-free.
__global__ __launch_bounds__(512) __attribute__((amdgpu_waves_per_eu(2, 2)))
void gru_seq(
    const float* __restrict__ xp,      // [T, 768]
    const float* __restrict__ Whh,     // [768, 256]
    const float* __restrict__ bhh,     // [768]
    const float* __restrict__ h0,      // [256] or nullptr (zeros)
    float* __restrict__ hs_out,        // [T, 256] or nullptr
    float* __restrict__ hT_out) {      // [256] or nullptr
  __shared__ uint hbuf[2][144];  // per buffer: 4 chunks x 36 dwords (72 f16)

  const int tid = threadIdx.x;
  const int p = tid >> 2;    // unit pair 0..127
  const int kc = tid & 3;    // k-chunk
  const int u0 = 2 * p;      // owned units u0, u0+1
  const bool gl = (kc == 0);

  // Weights: wreg[i][4c+j] = {W[rows[i]][64kc+8c+2j], W[rows[i]][64kc+8c+2j+1]}
  int rows[6];
  rows[0] = u0;          rows[1] = u0 + 1;
  rows[2] = 256 + u0;    rows[3] = 256 + u0 + 1;
  rows[4] = 512 + u0;    rows[5] = 512 + u0 + 1;
  h2 wreg[6][32];
#pragma unroll
  for (int i = 0; i < 6; ++i) {
    const float* wr = Whh + (size_t)rows[i] * HN + kc * 64;
#pragma unroll
    for (int c = 0; c < 8; ++c) {
      float4 a = *(const float4*)(wr + 8 * c);
      float4 b = *(const float4*)(wr + 8 * c + 4);
      wreg[i][4 * c + 0] = h2{(_Float16)a.x, (_Float16)a.y};
      wreg[i][4 * c + 1] = h2{(_Float16)a.z, (_Float16)a.w};
      wreg[i][4 * c + 2] = h2{(_Float16)b.x, (_Float16)b.y};
      wreg[i][4 * c + 3] = h2{(_Float16)b.z, (_Float16)b.w};
    }
  }

  // h-state (kc==0 lanes own units u0,u0+1) + n-gate bias pair.
  float hj0 = 0.f, hj1 = 0.f, bhn0 = 0.f, bhn1 = 0.f;
  const int ch = p >> 5;           // LDS chunk of u0
  const int eh = p & 31;           // dword elem within chunk
  if (gl) {
    if (h0) { float2 h = *(const float2*)(h0 + u0); hj0 = h.x; hj1 = h.y; }
    float2 b = *(const float2*)(bhh + 2 * HN + u0);
    bhn0 = b.x; bhn1 = b.y;
    h2 hp = h2{(_Float16)hj0, (_Float16)hj1};
    hbuf[0][36 * ch + eh] = __builtin_bit_cast(uint, hp);
  }
  __syncthreads();

  // Prefetch xp pairs for step 0.
  float xr0 = 0, xr1 = 0, xz0 = 0, xz1 = 0, xn0 = 0, xn1 = 0;
  if (gl) {
    float2 a = *(const float2*)(xp + u0);
    float2 b = *(const float2*)(xp + HN + u0);
    float2 c = *(const float2*)(xp + 2 * HN + u0);
    xr0 = a.x; xr1 = a.y; xz0 = b.x; xz1 = b.y; xn0 = c.x; xn1 = c.y;
  }

  for (int t = 0; t < TT; ++t) {
    // Prefetch next step's xp (stays in flight across the lgkm barrier).
    float nr0 = 0, nr1 = 0, nz0 = 0, nz1 = 0, nn0 = 0, nn1 = 0;
    if (gl && t + 1 < TT) {
      const float* xpt = xp + (size_t)(t + 1) * H3;
      float2 a = *(const float2*)(xpt + u0);
      float2 b = *(const float2*)(xpt + HN + u0);
      float2 c = *(const float2*)(xpt + 2 * HN + u0);
      nr0 = a.x; nr1 = a.y; nz0 = b.x; nz1 = b.y; nn0 = c.x; nn1 = c.y;
    }

    const uint* hb = hbuf[t & 1] + 36 * kc;  // this thread's k-chunk base

    float acc[6] = {0.f, 0.f, 0.f, 0.f, 0.f, 0.f};
#pragma unroll
    for (int c = 0; c < 8; ++c) {
      uint4 hv = *(const uint4*)(hb + 4 * c);  // 8 f16 of h, conflict-free
      const uint hw[4] = {hv.x, hv.y, hv.z, hv.w};
#pragma unroll
      for (int i = 0; i < 6; ++i)
#pragma unroll
        for (int j = 0; j < 4; ++j)
          acc[i] = fdot2(wreg[i][4 * c + j], __builtin_bit_cast(h2, hw[j]), acc[i]);
    }

    // Reduce 4 kc-partials within each quad (pure VALU DPP).
#pragma unroll
    for (int i = 0; i < 6; ++i) {
      float v = acc[i];
      v += dpp_qperm<0xB1>(v);  // xor 1
      v += dpp_qperm<0x4E>(v);  // xor 2
      acc[i] = v;
    }

    // Gates for units u0,u0+1 on kc==0 lanes (all inputs in registers).
    if (gl) {
      float r0 = 1.f / (1.f + __expf(-(xr0 + acc[0])));
      float r1 = 1.f / (1.f + __expf(-(xr1 + acc[1])));
      float z0 = 1.f / (1.f + __expf(-(xz0 + acc[2])));
      float z1 = 1.f / (1.f + __expf(-(xz1 + acc[3])));
      float n0 = 2.f / (1.f + __expf(-2.f * (xn0 + r0 * (acc[4] + bhn0)))) - 1.f;
      float n1 = 2.f / (1.f + __expf(-2.f * (xn1 + r1 * (acc[5] + bhn1)))) - 1.f;
      hj0 = (1.f - z0) * n0 + z0 * hj0;
      hj1 = (1.f - z1) * n1 + z1 * hj1;
      if (hs_out) *(float2*)(hs_out + (size_t)t * HN + u0) = make_float2(hj0, hj1);
      h2 hp = h2{(_Float16)hj0, (_Float16)hj1};
      hbuf[(t + 1) & 1][36 * ch + eh] = __builtin_bit_cast(uint, hp);
    }
    xr0 = nr0; xr1 = nr1; xz0 = nz0; xz1 = nz1; xn0 = nn0; xn1 = nn1;
    // lgkm-only barrier: orders hbuf writes vs next step's reads without
    // draining vmcnt (xp prefetch + hs stores stay in flight).
    asm volatile("s_waitcnt lgkmcnt(0)\n\ts_barrier" ::: "memory");
  }
  if (hT_out && gl) *(float2*)(hT_out + u0) = make_float2(hj0, hj1);
}

extern "C" void kernel_launch(void* const* d_in, const int* in_sizes, int n_in,
                              void* d_out, int out_size, void* d_ws, size_t ws_size,
                              hipStream_t stream) {
  const float* x     = (const float*)d_in[0];   // [1, 2048, 1739]
  const float* Wih_e = (const float*)d_in[2];   // [768, 1739]
  const float* Whh_e = (const float*)d_in[3];   // [768, 256]
  const float* bih_e = (const float*)d_in[4];   // [768]
  const float* bhh_e = (const float*)d_in[5];   // [768]
  const float* Wih_d = (const float*)d_in[6];
  const float* Whh_d = (const float*)d_in[7];
  const float* bih_d = (const float*)d_in[8];
  const float* bhh_d = (const float*)d_in[9];
  const float* Wout  = (const float*)d_in[10];  // [1739, 256]
  const float* bout  = (const float*)d_in[11];  // [1739]
  float* out = (float*)d_out;                   // [2048, 1, 1739]

  float* ws = (float*)d_ws;
  float* xpe  = ws;                              // 2048*768
  float* xpd  = xpe + (size_t)TT * H3;           // 2048*768
  float* hs   = xpd + (size_t)TT * H3;           // 2048*256
  float* henc = hs + (size_t)TT * HN;            // 256

  dim3 blk(256);
  // x-projections (b_hh folded in for r,z rows; n rows get b_ih only)
  gemm_abt<<<dim3(12, 32), blk, 0, stream>>>(x, TT, II, Wih_e, H3, bih_e, bhh_e, 2 * HN, xpe);
  gemm_abt<<<dim3(12, 32), blk, 0, stream>>>(x, TT, II, Wih_d, H3, bih_d, bhh_d, 2 * HN, xpd);
  // encoder scan -> henc
  gru_seq<<<1, 512, 0, stream>>>(xpe, Whh_e, bhh_e, nullptr, nullptr, henc);
  // decoder scan -> hs
  gru_seq<<<1, 512, 0, stream>>>(xpd, Whh_d, bhh_d, henc, hs, nullptr);
  // output projection
  gemm_abt<<<dim3(28, 32), blk, 0, stream>>>(hs, TT, HN, Wout, II, bout, nullptr, 0, out);
}